// Round 11
// baseline (679.790 us; speedup 1.0000x reference)
//
#include <hip/hip_runtime.h>
#include <hip/hip_bf16.h>

#define BB 128   // batch
#define TT 512   // time
#define EE 100   // embed dim
#define HH 128   // hidden
#define KK 12    // tags
#define VV 50257 // vocab
#define NB 4     // batches per block
#define NBLK 32  // blocks

typedef short bf16x8 __attribute__((ext_vector_type(8)));
typedef float f32x4  __attribute__((ext_vector_type(4)));

__device__ __forceinline__ unsigned short f2bf(float x) {
  __hip_bfloat16 h = __float2bfloat16(x);
  return *reinterpret_cast<unsigned short*>(&h);
}

__device__ __forceinline__ bf16x8 load8_bf(const float* p) {
  float4 a = *reinterpret_cast<const float4*>(p);
  float4 b = *reinterpret_cast<const float4*>(p + 4);
  bf16x8 r;
  r[0] = (short)f2bf(a.x); r[1] = (short)f2bf(a.y);
  r[2] = (short)f2bf(a.z); r[3] = (short)f2bf(a.w);
  r[4] = (short)f2bf(b.x); r[5] = (short)f2bf(b.y);
  r[6] = (short)f2bf(b.z); r[7] = (short)f2bf(b.w);
  return r;
}

// Wih fragment chunk with bias folded at k==EE, zeros past
__device__ __forceinline__ bf16x8 load8_bf_pad_bias(const float* row, int k0,
                                                    float bias) {
  bf16x8 r;
  #pragma unroll
  for (int i = 0; i < 8; ++i) {
    int k = k0 + i;
    unsigned short v = 0;
    if (k < EE) v = f2bf(row[k]);
    else if (k == EE) v = f2bf(bias);
    r[i] = (short)v;
  }
  return r;
}

// fast sigmoid / tanh: v_exp2 + v_rcp
__device__ __forceinline__ float sigr(float x) {
  float e = __builtin_amdgcn_exp2f(x * -1.44269504f);
  return __builtin_amdgcn_rcpf(1.0f + e);
}
__device__ __forceinline__ float tanhr(float x) {
  float e = __builtin_amdgcn_exp2f(x * -2.88539008f);
  return __fmaf_rn(2.0f, __builtin_amdgcn_rcpf(1.0f + e), -1.0f);
}

// ushort index of (row b, col k) in A-frag-ordered tile (lane-linear)
__device__ __forceinline__ int frag_idx(int b, int k) {
  return ((k >> 5) << 9) + ((b + (((k >> 3) & 3) << 4)) << 3) + (k & 7);
}

// ---------------------------------------------------------------------------
// Kernel 0: precast embed -> bf16 [V][128]; col 100 = 1.0 (bias slot), rest 0.
// ---------------------------------------------------------------------------
__global__ __launch_bounds__(256) void precast_kernel(
    const float* __restrict__ embed, unsigned short* __restrict__ ebf)
{
  int id = blockIdx.x * 256 + threadIdx.x;
  if (id >= VV * 16) return;
  int v = id >> 4, g = id & 15;
  const float* row = embed + (size_t)v * EE;
  bf16x8 o;
  #pragma unroll
  for (int i = 0; i < 8; ++i) {
    int k = g * 8 + i;
    unsigned short u = 0;
    if (k < EE) u = f2bf(row[k]);
    else if (k == EE) u = 0x3F80;   // 1.0 bf16
    o[i] = (short)u;
  }
  *reinterpret_cast<bf16x8*>(ebf + (size_t)id * 8) = o;
}

// ---------------------------------------------------------------------------
// Fused kernel. grid = 32 blocks (4 batches each) x 512 threads (8 waves).
// Batch lb (0..3) at MFMA row lb*4. Wave w owns e-strip [16w,16w+16) with 4
// gate-tiles {i,f,g,o}. The x-side GEMM (accx) is computed ONE STEP AHEAD
// from register-resident x, so the post-barrier critical path is only
// ds_read(h) -> 16 h-MFMA -> activations -> ds_write(h). x(s+2) prefetch
// issues at the top of the step so the barrier's vmcnt drain is ~free.
// Wave 0: emission MFMA (lag 1). Waves 4-7: Viterbi DP (lag 2).
// ---------------------------------------------------------------------------
__global__ __launch_bounds__(512, 2) void lstm_crf_fused(
    const int* __restrict__ sent, const unsigned short* __restrict__ ebf,
    const float* __restrict__ Wih, const float* __restrict__ Whh,
    const float* __restrict__ bih, const float* __restrict__ bhh,
    const float* __restrict__ h0, const float* __restrict__ c0,
    const float* __restrict__ Wtag, const float* __restrict__ btag,
    const float* __restrict__ trans, float* __restrict__ out)
{
  __shared__ unsigned char bp[256 * (NB * 12)];            // 12 KB nibble-packed
  __shared__ int sentl[NB * TT];                           // 8 KB sentence ids
  __shared__ __align__(16) unsigned short hfrag[2][2048];  // 8 KB h, frag order
  __shared__ __align__(16) float vit[NB * 16];
  __shared__ __align__(16) float trl[KK * 16];             // trl[j*16+i]=trans[i][j]
  __shared__ __align__(16) float ering[2][NB * 16];        // emission ring

  const int bg  = blockIdx.x;
  const int tid = threadIdx.x;
  const int w   = tid >> 6;         // wave 0..7
  const int l   = tid & 63;
  const int c   = l & 15;           // MFMA col within tile
  const int q   = l >> 4;           // row group; batch q at row q*4
  const int ew  = 16 * w + c;       // this lane's gate column (e)

  // ---- weights: 4 gate-tiles {i,f,g,o} of e-strip; bias in Wih k=100 ----
  bf16x8 wh[4][4], wx[4][4];
  #pragma unroll
  for (int tt = 0; tt < 4; ++tt) {
    const int gcol = tt * HH + ew;
    const float bias = bih[gcol] + bhh[gcol];
    #pragma unroll
    for (int kt = 0; kt < 4; ++kt) {
      const int k0 = kt * 32 + q * 8;
      wh[tt][kt] = load8_bf(Whh + (size_t)gcol * HH + k0);
      wx[tt][kt] = load8_bf_pad_bias(Wih + (size_t)gcol * EE, k0, bias);
    }
  }

  // ---- cell state: lane (q,c) holds c for batch q, e=ew ----
  float cst = c0[(size_t)(bg * NB + q) * HH + ew];

  // ---- emission weight fragments (wave 0) ----
  bf16x8 we[4];
  #pragma unroll
  for (int kt = 0; kt < 4; ++kt) {
    #pragma unroll
    for (int i = 0; i < 8; ++i) we[kt][i] = 0;
  }
  float bt = 0.f;
  if (w == 0 && c < KK) {
    #pragma unroll
    for (int kt = 0; kt < 4; ++kt)
      we[kt] = load8_bf(Wtag + (size_t)c * HH + kt * 32 + q * 8);
    bt = btag[c];
  }

  // ---- zero both h buffers (garbage rows must stay zero) ----
  {
    int4 z = {0, 0, 0, 0};
    reinterpret_cast<int4*>(hfrag)[tid] = z;
  }
  // ---- sentence-id table [NB][TT] ----
  #pragma unroll
  for (int i = 0; i < NB; ++i) {
    int idx = tid + i * 512;
    sentl[idx] = sent[(size_t)(bg * NB + (idx >> 9)) * TT + (idx & 511)];
  }
  // ---- transitions (transposed, padded) ----
  if (tid < KK * KK) {
    int i = tid / KK, jj = tid - i * KK;
    trl[jj * 16 + i] = trans[tid];
  }
  __syncthreads();   // zero-pass complete before h0 fill

  // ---- h0 -> hfrag[0] valid rows (row = lb*4) ----
  if (tid < NB * HH) {
    int lb = tid >> 7, k = tid & 127;
    hfrag[0][frag_idx(lb * 4, k)] = f2bf(h0[(size_t)(bg * NB + lb) * HH + k]);
  }

  // ---- x A-frag gather: lane row c -> batch c>>2 (garbage rows clamp) ----
  const int lbr  = c >> 2;
  const int koff = (l >> 4) * 8;    // ushort offset within x row
  const int* sentr = sent + (size_t)(bg * NB + lbr) * TT;

  // prologue: accx from x(0); xaB <- x(1)
  bf16x8 xaA[4], xaB[4];
  f32x4 accx[4];
  {
    const bf16x8* s0 = reinterpret_cast<const bf16x8*>(
        ebf + (size_t)sentr[0] * 128 + koff);
    const bf16x8* s1 = reinterpret_cast<const bf16x8*>(
        ebf + (size_t)sentr[1] * 128 + koff);
    #pragma unroll
    for (int kt = 0; kt < 4; ++kt) { xaA[kt] = s0[kt * 4]; xaB[kt] = s1[kt * 4]; }
    #pragma unroll
    for (int tt = 0; tt < 4; ++tt) {
      f32x4 z = {0.f, 0.f, 0.f, 0.f};
      accx[tt] = z;
    }
    #pragma unroll
    for (int kt = 0; kt < 4; ++kt) {
      #pragma unroll
      for (int tt = 0; tt < 4; ++tt)
        accx[tt] = __builtin_amdgcn_mfma_f32_16x16x32_bf16(xaA[kt], wx[tt][kt], accx[tt], 0, 0, 0);
    }
  }

  const int hw_off = frag_idx(q * 4, ew);
  int nib = 0;
  __syncthreads();

  // step s: gates(s) = accx (from x(s), computed at s-1) + h(s-1)@Whh.
  // xcur is dead (consumed at s-1) -> refill with x(s+2); xnxt = x(s+1)
  // feeds the accx recompute for step s+1.
  auto step = [&](int s, bf16x8 (&xcur)[4], bf16x8 (&xnxt)[4]) {
    const int rb = s & 1;

    // h(s-1) A-fragments
    bf16x8 ha[4];
    if (s <= TT) {
      const bf16x8* hr = reinterpret_cast<const bf16x8*>(&hfrag[rb][0]) + l;
      #pragma unroll
      for (int kt = 0; kt < 4; ++kt) ha[kt] = hr[kt * 64];
    }

    // prefetch x(s+2) early: full step to complete before barrier drain
    if (s + 2 < TT) {
      int id = sentl[lbr * TT + s + 2];
      const bf16x8* src = reinterpret_cast<const bf16x8*>(
          ebf + (size_t)id * 128 + koff);
      #pragma unroll
      for (int kt = 0; kt < 4; ++kt) xcur[kt] = src[kt * 4];
    }

    if (s < TT) {
      // take over the pipelined x contribution
      f32x4 acc[4];
      #pragma unroll
      for (int tt = 0; tt < 4; ++tt) acc[tt] = accx[tt];

      // recompute accx for step s+1 (register-only; fills ds_read shadow)
      if (s + 1 < TT) {
        #pragma unroll
        for (int tt = 0; tt < 4; ++tt) {
          f32x4 z = {0.f, 0.f, 0.f, 0.f};
          accx[tt] = z;
        }
        #pragma unroll
        for (int kt = 0; kt < 4; ++kt) {
          #pragma unroll
          for (int tt = 0; tt < 4; ++tt)
            accx[tt] = __builtin_amdgcn_mfma_f32_16x16x32_bf16(xnxt[kt], wx[tt][kt], accx[tt], 0, 0, 0);
        }
      }

      // h-side GEMM (critical path)
      #pragma unroll
      for (int kt = 0; kt < 4; ++kt) {
        #pragma unroll
        for (int tt = 0; tt < 4; ++tt)
          acc[tt] = __builtin_amdgcn_mfma_f32_16x16x32_bf16(ha[kt], wh[tt][kt], acc[tt], 0, 0, 0);
      }

      // cell update: lane-local, 1 row (batch q)
      float si = sigr(acc[0][0]);
      float sf = sigr(acc[1][0]);
      float tg = tanhr(acc[2][0]);
      float so = sigr(acc[3][0]);
      cst = __fmaf_rn(sf, cst, si * tg);
      hfrag[rb ^ 1][hw_off] = f2bf(so * tanhr(cst));
    }

    // wave 0: emissions E(t=s-1) -> ering (off critical path, uses ha regs)
    if (w == 0 && s >= 1 && s <= TT) {
      f32x4 accE = {0.f, 0.f, 0.f, 0.f};
      #pragma unroll
      for (int kt = 0; kt < 4; ++kt)
        accE = __builtin_amdgcn_mfma_f32_16x16x32_bf16(ha[kt], we[kt], accE, 0, 0, 0);
      ering[(s - 1) & 1][q * 16 + c] = accE[0] + bt;
    }

    // Viterbi DP (waves 4-7, lag 2): t = s-2, batch = w-4
    if (w >= 4 && s >= 2 && q == 0 && c < KK) {
      const int t_ = s - 2;
      const int b = w - 4;
      float Ev = ering[t_ & 1][b * 16 + c];
      float nv;
      if (t_ == 0) {
        nv = Ev;
      } else {
        float4 v0 = *reinterpret_cast<const float4*>(&vit[b * 16]);
        float4 v1 = *reinterpret_cast<const float4*>(&vit[b * 16 + 4]);
        float4 v2 = *reinterpret_cast<const float4*>(&vit[b * 16 + 8]);
        float4 t0 = *reinterpret_cast<const float4*>(&trl[c * 16]);
        float4 t1 = *reinterpret_cast<const float4*>(&trl[c * 16 + 4]);
        float4 t2 = *reinterpret_cast<const float4*>(&trl[c * 16 + 8]);
        float cand[KK] = {v0.x + t0.x, v0.y + t0.y, v0.z + t0.z, v0.w + t0.w,
                          v1.x + t1.x, v1.y + t1.y, v1.z + t1.z, v1.w + t1.w,
                          v2.x + t2.x, v2.y + t2.y, v2.z + t2.z, v2.w + t2.w};
        float g0 = fmaxf(fmaxf(cand[0], cand[1]), cand[2]);
        float g1 = fmaxf(fmaxf(cand[3], cand[4]), cand[5]);
        float g2 = fmaxf(fmaxf(cand[6], cand[7]), cand[8]);
        float g3 = fmaxf(fmaxf(cand[9], cand[10]), cand[11]);
        float best = fmaxf(fmaxf(g0, g1), fmaxf(g2, g3));
        int bi = 11;
        #pragma unroll
        for (int i = 10; i >= 0; --i) bi = (cand[i] == best) ? i : bi;   // first-max
        nv = Ev + best;
        if (t_ & 1) bp[(t_ >> 1) * (NB * 12) + b * 12 + c] =
                        (unsigned char)(nib | (bi << 4));
        else        nib = bi;
      }
      vit[b * 16 + c] = nv;
    }

    __syncthreads();
  };

  for (int s = 0; s < TT + 2; s += 2) {
    step(s, xaA, xaB);
    step(s + 1, xaB, xaA);
  }

  // ---- scores + backtrace (NB parallel chains) ----
  unsigned char* pb = reinterpret_cast<unsigned char*>(hfrag);  // reuse 8 KB
  if (tid < NB) {
    int b = tid;
    float best = vit[b * 16];
    int tag = 0;
    for (int jj = 1; jj < KK; ++jj) {
      float v = vit[b * 16 + jj];
      if (v > best) { best = v; tag = jj; }
    }
    out[bg * NB + b] = best;                    // scores
    pb[b * 512 + 511] = (unsigned char)tag;
    for (int t_ = TT - 1; t_ >= 1; --t_) {
      unsigned char byte = bp[(t_ >> 1) * (NB * 12) + b * 12 + tag];
      tag = (t_ & 1) ? (byte >> 4) & 15 : (byte & 15);
      pb[b * 512 + t_ - 1] = (unsigned char)tag;
    }
  }
  __syncthreads();

  #pragma unroll
  for (int i = 0; i < NB; ++i) {
    int idx = tid + i * 512;
    out[BB + (size_t)(bg * NB + (idx >> 9)) * TT + (idx & 511)] = (float)pb[idx];
  }
}

// ---------------------------------------------------------------------------
extern "C" void kernel_launch(void* const* d_in, const int* in_sizes, int n_in,
                              void* d_out, int out_size, void* d_ws, size_t ws_size,
                              hipStream_t stream) {
  const int*   sent  = (const int*)d_in[0];
  const float* h0    = (const float*)d_in[1];
  const float* c0    = (const float*)d_in[2];
  const float* embed = (const float*)d_in[3];
  const float* Wih   = (const float*)d_in[4];
  const float* Whh   = (const float*)d_in[5];
  const float* bih   = (const float*)d_in[6];
  const float* bhh   = (const float*)d_in[7];
  const float* Wtag  = (const float*)d_in[8];
  const float* btag  = (const float*)d_in[9];
  const float* trans = (const float*)d_in[10];
  float* out = (float*)d_out;
  unsigned short* ebf = (unsigned short*)d_ws;   // [V][128] bf16, 12.9 MB

  precast_kernel<<<(VV * 16 + 255) / 256, 256, 0, stream>>>(embed, ebf);
  lstm_crf_fused<<<NBLK, 512, 0, stream>>>(
      sent, ebf, Wih, Whh, bih, bhh, h0, c0, Wtag, btag, trans, out);
}

// Round 12
// 536.149 us; speedup vs baseline: 1.2679x; 1.2679x over previous
//
#include <hip/hip_runtime.h>
#include <hip/hip_bf16.h>

#define BB 128   // batch
#define TT 512   // time
#define EE 100   // embed dim
#define HH 128   // hidden
#define KK 12    // tags
#define VV 50257 // vocab
#define NB 8     // batches per block (recurrent)
#define NBLK 16  // recurrent blocks

typedef short bf16x8 __attribute__((ext_vector_type(8)));
typedef float f32x4  __attribute__((ext_vector_type(4)));

__device__ __forceinline__ unsigned short f2bf(float x) {
  __hip_bfloat16 h = __float2bfloat16(x);
  return *reinterpret_cast<unsigned short*>(&h);
}
__device__ __forceinline__ float bf2f(unsigned short u) {
  return __uint_as_float(((unsigned)u) << 16);
}

__device__ __forceinline__ bf16x8 load8_bf(const float* p) {
  float4 a = *reinterpret_cast<const float4*>(p);
  float4 b = *reinterpret_cast<const float4*>(p + 4);
  bf16x8 r;
  r[0] = (short)f2bf(a.x); r[1] = (short)f2bf(a.y);
  r[2] = (short)f2bf(a.z); r[3] = (short)f2bf(a.w);
  r[4] = (short)f2bf(b.x); r[5] = (short)f2bf(b.y);
  r[6] = (short)f2bf(b.z); r[7] = (short)f2bf(b.w);
  return r;
}

// Wih fragment chunk with bias folded at k==EE, zeros past
__device__ __forceinline__ bf16x8 load8_bf_pad_bias(const float* row, int k0,
                                                    float bias) {
  bf16x8 r;
  #pragma unroll
  for (int i = 0; i < 8; ++i) {
    int k = k0 + i;
    unsigned short v = 0;
    if (k < EE) v = f2bf(row[k]);
    else if (k == EE) v = f2bf(bias);
    r[i] = (short)v;
  }
  return r;
}

// fast sigmoid / tanh: v_exp2 + v_rcp
__device__ __forceinline__ float sigr(float x) {
  float e = __builtin_amdgcn_exp2f(x * -1.44269504f);
  return __builtin_amdgcn_rcpf(1.0f + e);
}
__device__ __forceinline__ float tanhr(float x) {
  float e = __builtin_amdgcn_exp2f(x * -2.88539008f);
  return __fmaf_rn(2.0f, __builtin_amdgcn_rcpf(1.0f + e), -1.0f);
}

// ushort index of (row b, col k) in A-frag-ordered tile (lane-linear)
__device__ __forceinline__ int frag_idx(int b, int k) {
  return ((k >> 5) << 9) + ((b + (((k >> 3) & 3) << 4)) << 3) + (k & 7);
}

// ---------------------------------------------------------------------------
// Kernel 0: precast embed -> bf16 [V][128]; col 100 = 1.0 (bias slot), rest 0.
// ---------------------------------------------------------------------------
__global__ __launch_bounds__(256) void precast_kernel(
    const float* __restrict__ embed, unsigned short* __restrict__ ebf)
{
  int id = blockIdx.x * 256 + threadIdx.x;
  if (id >= VV * 16) return;
  int v = id >> 4, g = id & 15;
  const float* row = embed + (size_t)v * EE;
  bf16x8 o;
  #pragma unroll
  for (int i = 0; i < 8; ++i) {
    int k = g * 8 + i;
    unsigned short u = 0;
    if (k < EE) u = f2bf(row[k]);
    else if (k == EE) u = 0x3F80;   // 1.0 bf16
    o[i] = (short)u;
  }
  *reinterpret_cast<bf16x8*>(ebf + (size_t)id * 8) = o;
}

// ---------------------------------------------------------------------------
// Kernel 1: Wih -> B-fragment table wbf[s8][tt][kt][lane] (bf16x8 each).
// gate col = tt*128 + 16*s8 + (l&15); k0 = kt*32 + (l>>4)*8; bias at k==100.
// ---------------------------------------------------------------------------
__global__ __launch_bounds__(256) void wprep_kernel(
    const float* __restrict__ Wih, const float* __restrict__ bih,
    const float* __restrict__ bhh, unsigned short* __restrict__ wbf)
{
  int id = blockIdx.x * 256 + threadIdx.x;   // 8192 frags
  if (id >= 8 * 4 * 4 * 64) return;
  int l = id & 63, kt = (id >> 6) & 3, tt = (id >> 8) & 3, s8 = id >> 10;
  int gcol = tt * HH + 16 * s8 + (l & 15);
  int k0 = kt * 32 + (l >> 4) * 8;
  float bias = bih[gcol] + bhh[gcol];
  bf16x8 r = load8_bf_pad_bias(Wih + (size_t)gcol * EE, k0, bias);
  *reinterpret_cast<bf16x8*>(wbf + (size_t)id * 8) = r;
}

// ---------------------------------------------------------------------------
// Kernel 2: pregates GEMM. P16[flat(b,t)][e][tt] bf16 quad-interleaved.
// grid = 1024 blocks x 256 threads (4 waves); wave -> row-tile rt = blk*4+w
// (16 consecutive t of one b). 8 e-strips x {i,f,g,o} x 4 K-frags = 128 MFMA.
// ---------------------------------------------------------------------------
__global__ __launch_bounds__(256, 2) void pregates_kernel(
    const int* __restrict__ sent, const unsigned short* __restrict__ ebf,
    const unsigned short* __restrict__ wbf, unsigned short* __restrict__ P16)
{
  const int w = threadIdx.x >> 6, l = threadIdx.x & 63;
  const int c = l & 15, q = l >> 4;
  const int rt = blockIdx.x * 4 + w;
  const int flat = rt * 16 + c;               // this lane's A row
  const int b = flat >> 9, t = flat & 511;
  const int id = sent[b * TT + t];

  bf16x8 xa[4];
  #pragma unroll
  for (int kt = 0; kt < 4; ++kt)
    xa[kt] = *reinterpret_cast<const bf16x8*>(
        ebf + (size_t)id * 128 + kt * 32 + q * 8);

  const bf16x8* wb = reinterpret_cast<const bf16x8*>(wbf);
  #pragma unroll
  for (int s8 = 0; s8 < 8; ++s8) {
    f32x4 acc[4];
    #pragma unroll
    for (int tt = 0; tt < 4; ++tt) {
      f32x4 z = {0.f, 0.f, 0.f, 0.f};
      acc[tt] = z;
    }
    #pragma unroll
    for (int kt = 0; kt < 4; ++kt) {
      #pragma unroll
      for (int tt = 0; tt < 4; ++tt)
        acc[tt] = __builtin_amdgcn_mfma_f32_16x16x32_bf16(
            xa[kt], wb[((s8 * 4 + tt) * 4 + kt) * 64 + l], acc[tt], 0, 0, 0);
    }
    const int e = s8 * 16 + c;
    #pragma unroll
    for (int r4 = 0; r4 < 4; ++r4) {
      int fr = rt * 16 + q * 4 + r4;          // D row = (l>>4)*4 + reg
      ushort4 o = make_ushort4(f2bf(acc[0][r4]), f2bf(acc[1][r4]),
                               f2bf(acc[2][r4]), f2bf(acc[3][r4]));
      *reinterpret_cast<ushort4*>(P16 + ((size_t)fr * 128 + e) * 4) = o;
    }
  }
}

// ---------------------------------------------------------------------------
// Kernel 3: recurrent LSTM + emissions + Viterbi + backtrace.
// grid = 16 blocks (8 batches) x 512 threads (8 waves). r9 skeleton: batch
// lb at MFMA row ((lb>>1)*4 + (lb&1)); wave w owns e-strip [16w,16w+16) with
// gate-tiles {i,f,g,o}; x-side GEMM replaced by a P16 quad load (bf16->f32
// acc init). Wave 0: emission (lag 1). Waves 4-7: Viterbi (lag 2).
// 56KB dynamic LDS pads the block to ~90KB -> exactly 1 block/CU.
// ---------------------------------------------------------------------------
__global__ __launch_bounds__(512, 2) void lstm_crf_fused(
    const unsigned short* __restrict__ P16, const float* __restrict__ Whh,
    const float* __restrict__ h0, const float* __restrict__ c0,
    const float* __restrict__ Wtag, const float* __restrict__ btag,
    const float* __restrict__ trans, float* __restrict__ out)
{
  __shared__ unsigned char bp[256 * (NB * 12)];            // 24 KB nibble-packed
  __shared__ __align__(16) unsigned short hfrag[2][2048];  // 8 KB h, frag order
  __shared__ __align__(16) float vit[NB * 16];
  __shared__ __align__(16) float trl[KK * 16];             // trl[j*16+i]=trans[i][j]
  __shared__ __align__(16) float ering[2][NB * 16];        // emission ring
  extern __shared__ char dynpad[];                         // occupancy limiter
  (void)dynpad;

  const int bg  = blockIdx.x;
  const int tid = threadIdx.x;
  const int w   = tid >> 6;         // wave 0..7
  const int l   = tid & 63;
  const int c   = l & 15;           // MFMA col within tile
  const int q   = l >> 4;           // row group; batches q*2+{0,1} at rows q*4+{0,1}
  const int ew  = 16 * w + c;       // this lane's gate column (e)

  // ---- weights: 4 gate-tiles {i,f,g,o} of e-strip (h-side only) ----
  bf16x8 wh[4][4];
  #pragma unroll
  for (int tt = 0; tt < 4; ++tt) {
    const int gcol = tt * HH + ew;
    #pragma unroll
    for (int kt = 0; kt < 4; ++kt)
      wh[tt][kt] = load8_bf(Whh + (size_t)gcol * HH + kt * 32 + q * 8);
  }

  // ---- cell state: lane (q,c) holds c for batches q*2+r, e=ew ----
  float cst[2];
  #pragma unroll
  for (int r = 0; r < 2; ++r)
    cst[r] = c0[(size_t)(bg * NB + q * 2 + r) * HH + ew];

  // ---- emission weight fragments (wave 0) ----
  bf16x8 we[4];
  #pragma unroll
  for (int kt = 0; kt < 4; ++kt) {
    #pragma unroll
    for (int i = 0; i < 8; ++i) we[kt][i] = 0;
  }
  float bt = 0.f;
  if (w == 0 && c < KK) {
    #pragma unroll
    for (int kt = 0; kt < 4; ++kt)
      we[kt] = load8_bf(Wtag + (size_t)c * HH + kt * 32 + q * 8);
    bt = btag[c];
  }

  // ---- zero both h buffers (garbage rows must stay zero) ----
  {
    int4 z = {0, 0, 0, 0};
    reinterpret_cast<int4*>(hfrag)[tid] = z;
  }
  // ---- transitions (transposed, padded) ----
  if (tid < KK * KK) {
    int i = tid / KK, jj = tid - i * KK;
    trl[jj * 16 + i] = trans[tid];
  }
  __syncthreads();   // zero-pass complete before h0 fill

  // ---- h0 -> hfrag[0] valid rows ----
  for (int idx = tid; idx < NB * HH; idx += 512) {
    int lb = idx >> 7, k = idx & 127;
    int row = ((lb >> 1) << 2) + (lb & 1);
    hfrag[0][frag_idx(row, k)] = f2bf(h0[(size_t)(bg * NB + lb) * HH + k]);
  }

  // ---- P stream: per lane, rows r=0,1 -> batches bg*8+q*2+r ----
  const unsigned short* pb0 =
      P16 + (size_t)(bg * NB + q * 2 + 0) * (TT * 512) + ew * 4;
  const unsigned short* pb1 =
      P16 + (size_t)(bg * NB + q * 2 + 1) * (TT * 512) + ew * 4;
  ushort4 pA[2], pB[2];
  pA[0] = *reinterpret_cast<const ushort4*>(pb0);
  pA[1] = *reinterpret_cast<const ushort4*>(pb1);
  pB[0] = *reinterpret_cast<const ushort4*>(pb0 + 512);
  pB[1] = *reinterpret_cast<const ushort4*>(pb1 + 512);

  const int hw_off = frag_idx(q * 4, ew);
  int nib = 0;
  __syncthreads();

  auto step = [&](int s, ushort4 (&pcur)[2]) {
    const int rb = s & 1;

    // h(s-1) A-fragments
    bf16x8 ha[4];
    if (s <= TT) {
      const bf16x8* hr = reinterpret_cast<const bf16x8*>(&hfrag[rb][0]) + l;
      #pragma unroll
      for (int kt = 0; kt < 4; ++kt) ha[kt] = hr[kt * 64];
    }

    if (s < TT) {
      // acc init from pregate quads (x@Wih^T + bias, computed offline)
      f32x4 acc[4];
      #pragma unroll
      for (int tt = 0; tt < 4; ++tt) {
        f32x4 z = {0.f, 0.f, 0.f, 0.f};
        acc[tt] = z;
      }
      acc[0][0] = bf2f(pcur[0].x); acc[1][0] = bf2f(pcur[0].y);
      acc[2][0] = bf2f(pcur[0].z); acc[3][0] = bf2f(pcur[0].w);
      acc[0][1] = bf2f(pcur[1].x); acc[1][1] = bf2f(pcur[1].y);
      acc[2][1] = bf2f(pcur[1].z); acc[3][1] = bf2f(pcur[1].w);

      // prefetch P(s+2) into the now-dead buffer
      if (s + 2 < TT) {
        pcur[0] = *reinterpret_cast<const ushort4*>(pb0 + (size_t)(s + 2) * 512);
        pcur[1] = *reinterpret_cast<const ushort4*>(pb1 + (size_t)(s + 2) * 512);
      }

      // h-side GEMM (critical path)
      #pragma unroll
      for (int kt = 0; kt < 4; ++kt) {
        #pragma unroll
        for (int tt = 0; tt < 4; ++tt)
          acc[tt] = __builtin_amdgcn_mfma_f32_16x16x32_bf16(ha[kt], wh[tt][kt], acc[tt], 0, 0, 0);
      }

      // cell update: lane-local, 2 rows
      unsigned short* hwp = &hfrag[rb ^ 1][hw_off];
      #pragma unroll
      for (int r = 0; r < 2; ++r) {
        float si = sigr(acc[0][r]);
        float sf = sigr(acc[1][r]);
        float tg = tanhr(acc[2][r]);
        float so = sigr(acc[3][r]);
        cst[r] = __fmaf_rn(sf, cst[r], si * tg);
        hwp[r * 8] = f2bf(so * tanhr(cst[r]));
      }
    } else if (s + 2 < TT) {
      // unreachable (s >= TT implies s+2 >= TT+2), keeps pcur defined
    }

    // wave 0: emissions E(t=s-1) -> ering
    if (w == 0 && s >= 1 && s <= TT) {
      f32x4 accE = {0.f, 0.f, 0.f, 0.f};
      #pragma unroll
      for (int kt = 0; kt < 4; ++kt)
        accE = __builtin_amdgcn_mfma_f32_16x16x32_bf16(ha[kt], we[kt], accE, 0, 0, 0);
      float* er = &ering[(s - 1) & 1][0];
      #pragma unroll
      for (int r = 0; r < 2; ++r)
        er[(q * 2 + r) * 16 + c] = accE[r] + bt;
    }

    // Viterbi DP (waves 4-7, lag 2): t = s-2, batch = (w-4)*2+q
    if (w >= 4 && s >= 2 && q < 2 && c < KK) {
      const int t_ = s - 2;
      const int b = (w - 4) * 2 + q;
      float Ev = ering[t_ & 1][b * 16 + c];
      float nv;
      if (t_ == 0) {
        nv = Ev;
      } else {
        float4 v0 = *reinterpret_cast<const float4*>(&vit[b * 16]);
        float4 v1 = *reinterpret_cast<const float4*>(&vit[b * 16 + 4]);
        float4 v2 = *reinterpret_cast<const float4*>(&vit[b * 16 + 8]);
        float4 t0 = *reinterpret_cast<const float4*>(&trl[c * 16]);
        float4 t1 = *reinterpret_cast<const float4*>(&trl[c * 16 + 4]);
        float4 t2 = *reinterpret_cast<const float4*>(&trl[c * 16 + 8]);
        float cand[KK] = {v0.x + t0.x, v0.y + t0.y, v0.z + t0.z, v0.w + t0.w,
                          v1.x + t1.x, v1.y + t1.y, v1.z + t1.z, v1.w + t1.w,
                          v2.x + t2.x, v2.y + t2.y, v2.z + t2.z, v2.w + t2.w};
        float g0 = fmaxf(fmaxf(cand[0], cand[1]), cand[2]);
        float g1 = fmaxf(fmaxf(cand[3], cand[4]), cand[5]);
        float g2 = fmaxf(fmaxf(cand[6], cand[7]), cand[8]);
        float g3 = fmaxf(fmaxf(cand[9], cand[10]), cand[11]);
        float best = fmaxf(fmaxf(g0, g1), fmaxf(g2, g3));
        int bi = 11;
        #pragma unroll
        for (int i = 10; i >= 0; --i) bi = (cand[i] == best) ? i : bi;   // first-max
        nv = Ev + best;
        if (t_ & 1) bp[(t_ >> 1) * (NB * 12) + b * 12 + c] =
                        (unsigned char)(nib | (bi << 4));
        else        nib = bi;
      }
      vit[b * 16 + c] = nv;
    }

    __syncthreads();
  };

  for (int s = 0; s < TT + 2; s += 2) {
    step(s, pA);
    step(s + 1, pB);
  }

  // ---- scores + backtrace (NB parallel chains) ----
  unsigned char* pb = reinterpret_cast<unsigned char*>(hfrag);  // reuse 8 KB
  if (tid < NB) {
    int b = tid;
    float best = vit[b * 16];
    int tag = 0;
    for (int jj = 1; jj < KK; ++jj) {
      float v = vit[b * 16 + jj];
      if (v > best) { best = v; tag = jj; }
    }
    out[bg * NB + b] = best;                    // scores
    pb[b * 512 + 511] = (unsigned char)tag;
    for (int t_ = TT - 1; t_ >= 1; --t_) {
      unsigned char byte = bp[(t_ >> 1) * (NB * 12) + b * 12 + tag];
      tag = (t_ & 1) ? (byte >> 4) & 15 : (byte & 15);
      pb[b * 512 + t_ - 1] = (unsigned char)tag;
    }
  }
  __syncthreads();

  #pragma unroll
  for (int i = 0; i < NB; ++i) {
    int idx = tid + i * 512;
    out[BB + (size_t)(bg * NB + (idx >> 9)) * TT + (idx & 511)] = (float)pb[idx];
  }
}

// ---------------------------------------------------------------------------
extern "C" void kernel_launch(void* const* d_in, const int* in_sizes, int n_in,
                              void* d_out, int out_size, void* d_ws, size_t ws_size,
                              hipStream_t stream) {
  const int*   sent  = (const int*)d_in[0];
  const float* h0    = (const float*)d_in[1];
  const float* c0    = (const float*)d_in[2];
  const float* embed = (const float*)d_in[3];
  const float* Wih   = (const float*)d_in[4];
  const float* Whh   = (const float*)d_in[5];
  const float* bih   = (const float*)d_in[6];
  const float* bhh   = (const float*)d_in[7];
  const float* Wtag  = (const float*)d_in[8];
  const float* btag  = (const float*)d_in[9];
  const float* trans = (const float*)d_in[10];
  float* out = (float*)d_out;

  // workspace layout (bytes): ebf [V*128 bf16] | wbf [128KB] | P16 [64MB]
  unsigned short* ebf = (unsigned short*)d_ws;
  unsigned short* wbf = ebf + (size_t)VV * 128;
  unsigned short* P16 = wbf + 8192 * 8;

  precast_kernel<<<(VV * 16 + 255) / 256, 256, 0, stream>>>(embed, ebf);
  wprep_kernel<<<32, 256, 0, stream>>>(Wih, bih, bhh, wbf);
  pregates_kernel<<<(BB * TT / 16) / 4, 256, 0, stream>>>(sent, ebf, wbf, P16);
  lstm_crf_fused<<<NBLK, 512, 56 * 1024, stream>>>(
      P16, Whh, h0, c0, Wtag, btag, trans, out);
}